// Round 5
// baseline (90.927 us; speedup 1.0000x reference)
//
#include <hip/hip_runtime.h>

// 20-qubit feature map: 4 layers of (RX·RY per wire + CNOT chain), <Z_i> outputs.
// wire w <-> bit (19-w). CNOT chain == gray perm: new[y] = old[y ^ (y>>1)], always
// folded into the next read (stageA MODE1) or the final expectation (stageB FUSE).
// Layer 1 on |0..0> = product state, computed in-register in stageA MODE0.
//
// R5: 11/9 bit split, both stages 512 blocks x 256 threads (2 blocks/CU for TLP).
// A: block = fixed bits 11..19 (Hf), owns bits 0..10. regs=b0..2, lanes=b3..8, wv=b9..10.
// B: block = fixed bits 2..10 (bb), owns bits {0,1,11..19}. regs=b11..13,
//    lanes: l0,l1=b0,b1; l2..l5=b14..17; wv=b18,b19.

#define NW 20

__device__ __forceinline__ float2 cmul(float2 a, float2 b) {
    return make_float2(a.x*b.x - a.y*b.y, a.x*b.y + a.y*b.x);
}

__device__ __forceinline__ void apply_gate(float2& a0, float2& a1,
                                           float2 u00, float2 u01,
                                           float2 u10, float2 u11) {
    float2 b0, b1;
    b0.x = u00.x*a0.x - u00.y*a0.y + u01.x*a1.x - u01.y*a1.y;
    b0.y = u00.x*a0.y + u00.y*a0.x + u01.x*a1.y + u01.y*a1.x;
    b1.x = u10.x*a0.x - u10.y*a0.y + u11.x*a1.x - u11.y*a1.y;
    b1.y = u10.x*a0.y + u10.y*a0.x + u11.x*a1.y + u11.y*a1.x;
    a0 = b0; a1 = b1;
}

__device__ __forceinline__ float2 shflx(float2 v, int m) {
    float2 r;
    r.x = __shfl_xor(v.x, m, 64);
    r.y = __shfl_xor(v.y, m, 64);
    return r;
}

// Apply the 2x2 gate (at Gw) pairing amps that differ in reg-bit A.
template<int A>
__device__ __forceinline__ void gate_regbit(float2 (&amp)[8], const float2* __restrict__ Gw) {
    float2 u00 = Gw[0], u01 = Gw[1], u10 = Gw[2], u11 = Gw[3];
    #pragma unroll
    for (int r = 0; r < 8; r++)
        if (!(r & (1 << A)))
            apply_gate(amp[r], amp[r | (1 << A)], u00, u01, u10, u11);
}

// Swap reg-bit A with the lane bit selected by mask LM (butterfly exchange).
// lane_b=0 sends hi, lane_b=1 sends lo (R4-verified).
template<int A, int LM>
__device__ __forceinline__ void swap_reg_lane(float2 (&amp)[8], unsigned lane) {
    bool hb = (lane & (unsigned)LM) != 0u;
    #pragma unroll
    for (int r = 0; r < 8; r++) {
        if (!(r & (1 << A))) {
            float2 lo = amp[r], hi = amp[r | (1 << A)];
            float2 xs = hb ? lo : hi;
            float2 ys = shflx(xs, LM);
            amp[r]            = hb ? ys : lo;
            amp[r | (1 << A)] = hb ? hi : ys;
        }
    }
}

// U = RY(x)*RX(x), half-angle h = x/2. G[w*4 + r*2 + c] = U^w[r][c].
__global__ void prep_gates(const float* __restrict__ x, float2* __restrict__ G) {
    int w = threadIdx.x;
    if (w < NW) {
        float h = 0.5f * x[w];
        float c = cosf(h), s = sinf(h);
        float cc = c*c, ss = s*s, cs = c*s;
        G[w*4+0] = make_float2(cc,  ss);
        G[w*4+1] = make_float2(-cs, -cs);
        G[w*4+2] = make_float2(cs,  -cs);
        G[w*4+3] = make_float2(cc,  -ss);
    }
}

// Stage A: gates on bits 0..10 (wires 19..9). Block = logical bits 11..19 (Hf).
template<int MODE>
__global__ __launch_bounds__(256) void stageA(const float2* __restrict__ src,
                                              float2* __restrict__ dst,
                                              const float2* __restrict__ G) {
    __shared__ float2 lds[2048];
    const unsigned t = threadIdx.x;
    const unsigned lane = t & 63u, wv = t >> 6;          // wv: 2 bits (b9,b10)
    const unsigned Hf  = blockIdx.x;                     // logical bits 11..19
    const unsigned Hp  = Hf ^ (Hf >> 1);                 // physical bits 11..19
    const unsigned inj = (Hf & 1u) << 10;
    const unsigned lb  = (wv << 9) | (lane << 3);        // logical low-11 base
    const unsigned gb  = (lb ^ (lb >> 1)) ^ inj;         // gray11(lb)^inj; low3 = (lane&1)<<2

    float2 amp[8];
    if (MODE == 1) {
        // phys low-11 = gb ^ gray3(k): aligned 64B group at gb&~7.
        const float4* q = (const float4*)(src + ((size_t)Hp << 11) + (gb & ~7u));
        float4 q0 = q[0], q1 = q[1], q2 = q[2], q3 = q[3];
        float2 e0 = make_float2(q0.x,q0.y), e1 = make_float2(q0.z,q0.w);
        float2 e2 = make_float2(q1.x,q1.y), e3 = make_float2(q1.z,q1.w);
        float2 e4 = make_float2(q2.x,q2.y), e5 = make_float2(q2.z,q2.w);
        float2 e6 = make_float2(q3.x,q3.y), e7 = make_float2(q3.z,q3.w);
        bool f = (gb & 4u) != 0u;     // amp[k] = e[(f?4:0) ^ gray3(k)]
        amp[0] = f ? e4 : e0;  amp[1] = f ? e5 : e1;
        amp[2] = f ? e7 : e3;  amp[3] = f ? e6 : e2;
        amp[4] = f ? e2 : e6;  amp[5] = f ? e3 : e7;
        amp[6] = f ? e1 : e5;  amp[7] = f ? e0 : e4;
    } else {
        // amp(Y) = prod_b U^{19-b}[z_b][0], z = gray20(Y); z low-11 = gb ^ gray3(k).
        float2 P = make_float2(1.0f, 0.0f);
        #pragma unroll
        for (int b = 11; b <= 19; b++)
            P = cmul(P, G[(19-b)*4 + (int)((Hp >> (b-11)) & 1u)*2]);
        #pragma unroll
        for (int b = 3; b <= 10; b++)
            P = cmul(P, G[(19-b)*4 + (int)((gb >> b) & 1u)*2]);
        float2 Tt[8];
        #pragma unroll
        for (int j = 0; j < 8; j++) {
            float2 v = cmul(G[18*4 + ((j>>1)&1)*2], G[19*4 + (j&1)*2]);
            v = cmul(G[17*4 + ((j>>2)&1)*2], v);
            Tt[j] = cmul(P, v);
        }
        bool f = (gb & 4u) != 0u;     // amp[k] = Tt[(f?4:0) ^ gray3(k)]
        amp[0] = f ? Tt[4] : Tt[0];  amp[1] = f ? Tt[5] : Tt[1];
        amp[2] = f ? Tt[7] : Tt[3];  amp[3] = f ? Tt[6] : Tt[2];
        amp[4] = f ? Tt[2] : Tt[6];  amp[5] = f ? Tt[3] : Tt[7];
        amp[6] = f ? Tt[1] : Tt[5];  amp[7] = f ? Tt[0] : Tt[4];
    }

    // bits 0,1,2 (wires 19,18,17) on regs
    gate_regbit<0>(amp, G + 19*4);
    gate_regbit<1>(amp, G + 18*4);
    gate_regbit<2>(amp, G + 17*4);
    // regs <-> lane bits 0..2 (amp bits 3..5)
    swap_reg_lane<0,1>(amp, lane);
    swap_reg_lane<1,2>(amp, lane);
    swap_reg_lane<2,4>(amp, lane);
    gate_regbit<0>(amp, G + 16*4);   // bit 3
    gate_regbit<1>(amp, G + 15*4);   // bit 4
    gate_regbit<2>(amp, G + 14*4);   // bit 5
    // regs <-> lane bits 3..5 (amp bits 6..8)
    swap_reg_lane<0,8>(amp, lane);
    swap_reg_lane<1,16>(amp, lane);
    swap_reg_lane<2,32>(amp, lane);
    gate_regbit<0>(amp, G + 13*4);   // bit 6
    gate_regbit<1>(amp, G + 12*4);   // bit 7
    gate_regbit<2>(amp, G + 11*4);   // bit 8
    // LDS exchange: amp map now b0..5=lane, b6..8=regs, b9..10=wv.
    // Bring bits 9,10 into regs (keep bit 6 as reg bit 0).
    #pragma unroll
    for (int k = 0; k < 8; k++) lds[lane | ((unsigned)k << 6) | (wv << 9)] = amp[k];
    __syncthreads();
    #pragma unroll
    for (int k = 0; k < 8; k++)
        amp[k] = lds[lane | (((unsigned)k & 1u) << 6) | (wv << 7) | (((unsigned)k >> 1) << 9)];
    // regs: k0=b6 (gated), k1=b9, k2=b10
    gate_regbit<1>(amp, G + 10*4);   // bit 9  (wire 10)
    gate_regbit<2>(amp, G +  9*4);   // bit 10 (wire 9)
    // store logical order (coalesced 512B runs per k)
    float2* d = dst + ((size_t)Hf << 11);
    #pragma unroll
    for (int k = 0; k < 8; k++)
        d[lane | (((unsigned)k & 1u) << 6) | (wv << 7) | (((unsigned)k >> 1) << 9)] = amp[k];
}

// Stage B: gates on bits 11..19 (wires 8..0); in-place; block = bits 2..10 (bb).
// FUSE=1: final layer -> fold last gray perm, accumulate <Z_w> partials (no store).
template<int FUSE>
__global__ __launch_bounds__(256) void stageB(float2* __restrict__ st,
                                              const float2* __restrict__ G,
                                              float* __restrict__ partial) {
    __shared__ float2 lds[2048];
    const unsigned t = threadIdx.x, lane = t & 63u, wv = t >> 6;  // wv: b18,b19
    const unsigned bb = blockIdx.x;                               // bits 2..10
    const unsigned l01 = lane & 3u, l2345 = (lane >> 2) & 15u;    // b0,b1 ; b14..17

    float2 amp[8];
    #pragma unroll
    for (int k = 0; k < 8; k++) {
        unsigned idx = l01 | (bb << 2) | ((unsigned)k << 11) | (l2345 << 14) | (wv << 18);
        amp[k] = st[idx];
    }
    gate_regbit<0>(amp, G + 8*4);   // bit 11 (wire 8)
    gate_regbit<1>(amp, G + 7*4);   // bit 12
    gate_regbit<2>(amp, G + 6*4);   // bit 13
    // regs(b11,b12,b13) <-> lanes l2,l3,l4 (b14,b15,b16)
    swap_reg_lane<0,4>(amp, lane);
    swap_reg_lane<1,8>(amp, lane);
    swap_reg_lane<2,16>(amp, lane);
    gate_regbit<0>(amp, G + 5*4);   // bit 14 (wire 5)
    gate_regbit<1>(amp, G + 4*4);   // bit 15
    gate_regbit<2>(amp, G + 3*4);   // bit 16
    // LDS exchange. amp map: l0=b0,l1=b1,l2=b11,l3=b12,l4=b13,l5=b17; k=b14,b15,b16; wv=b18,b19.
    // addr bits: a0..a5 = lane, a6..a8 = k, a9..a10 = wv.
    #pragma unroll
    for (int k = 0; k < 8; k++) lds[lane | ((unsigned)k << 6) | (wv << 9)] = amp[k];
    __syncthreads();
    // new layout: lanes' l0,l1=b0,b1; l2..l4=b11..13; l5=b14; wv'=b15,b16; regs=b17,b18,b19.
    #pragma unroll
    for (int k = 0; k < 8; k++) {
        unsigned a = (lane & 31u) | (((unsigned)k & 1u) << 5) | (((lane >> 5) & 1u) << 6)
                   | ((wv & 1u) << 7) | (((wv >> 1) & 1u) << 8)
                   | ((((unsigned)k >> 1) & 1u) << 9) | ((((unsigned)k >> 2) & 1u) << 10);
        amp[k] = lds[a];
    }
    gate_regbit<0>(amp, G + 2*4);   // bit 17 (wire 2)
    gate_regbit<1>(amp, G + 1*4);   // bit 18 (wire 1)
    gate_regbit<2>(amp, G + 0*4);   // bit 19 (wire 0)

    if (!FUSE) {
        #pragma unroll
        for (int k = 0; k < 8; k++) {
            unsigned idx = (lane & 3u) | (bb << 2) | (((lane >> 2) & 7u) << 11)
                         | (((lane >> 5) & 1u) << 14) | (wv << 15)
                         | (((unsigned)k & 1u) << 17) | ((((unsigned)k >> 1) & 1u) << 18)
                         | ((((unsigned)k >> 2) & 1u) << 19);
            st[idx] = amp[k];
        }
    } else {
        // final perm y = invgray(Y); sign for wire w is y bit (19-w).
        // regs k: k0=Y17, k1=Y18, k2=Y19 (same mapping as R4 -> formulas verbatim).
        float p[8];
        #pragma unroll
        for (int k = 0; k < 8; k++) p[k] = amp[k].x*amp[k].x + amp[k].y*amp[k].y;
        float Se = p[0]+p[3]+p[5]+p[6];                             // parity(k)=0
        float So = p[1]+p[2]+p[4]+p[7];
        float D  = Se - So;                                          // wire 2 (y17)
        float S0 = (p[0]+p[1]+p[2]+p[3]) - (p[4]+p[5]+p[6]+p[7]);    // wire 0 (y19=k2)
        float S1 = (p[0]+p[1]+p[6]+p[7]) - (p[2]+p[3]+p[4]+p[5]);    // wire 1 (y18=k1^k2)
        unsigned v = (lane & 3u) | (bb << 2) | (((lane >> 2) & 7u) << 11)
                   | (((lane >> 5) & 1u) << 14) | (wv << 15);        // Y bits 0..16
        unsigned cm = v; cm ^= cm >> 1; cm ^= cm >> 2; cm ^= cm >> 4;
        cm ^= cm >> 8; cm ^= cm >> 16;                               // cm_b = XOR_{j=b..16} Y_j
        float acc[NW];
        acc[0] = S0; acc[1] = S1; acc[2] = D;
        #pragma unroll
        for (int w = 3; w < NW; w++)
            acc[w] = ((cm >> (19 - w)) & 1u) ? -D : D;

        __syncthreads();                 // done with gate LDS; reuse for reduction
        float* red = (float*)lds;
        #pragma unroll
        for (int w = 0; w < NW; w++) {
            float s = acc[w];
            #pragma unroll
            for (int off = 32; off; off >>= 1) s += __shfl_down(s, off, 64);
            if (lane == 0) red[wv*NW + w] = s;
        }
        __syncthreads();
        if (t < NW) {
            float s = 0.0f;
            #pragma unroll
            for (int w4 = 0; w4 < 4; w4++) s += red[w4*NW + (int)t];
            partial[bb*NW + t] = s;
        }
    }
}

__global__ __launch_bounds__(512) void reduce_out(const float* __restrict__ partial,
                                                  float* __restrict__ out) {
    __shared__ float red[8*NW];
    unsigned t = threadIdx.x;
    float vals[NW];
    #pragma unroll
    for (int w = 0; w < NW; w++) vals[w] = partial[t*NW + w];
    #pragma unroll
    for (int w = 0; w < NW; w++) {
        float v = vals[w];
        #pragma unroll
        for (int off = 32; off; off >>= 1) v += __shfl_down(v, off, 64);
        if ((t & 63u) == 0u) red[(t >> 6)*NW + w] = v;
    }
    __syncthreads();
    if (t < NW) {
        float s = 0.0f;
        #pragma unroll
        for (int w8 = 0; w8 < 8; w8++) s += red[w8*NW + (int)t];
        out[t] = s;
    }
}

extern "C" void kernel_launch(void* const* d_in, const int* in_sizes, int n_in,
                              void* d_out, int out_size, void* d_ws, size_t ws_size,
                              hipStream_t stream) {
    (void)in_sizes; (void)n_in; (void)out_size; (void)ws_size;
    const float* x = (const float*)d_in[0];
    float* out = (float*)d_out;

    char* ws = (char*)d_ws;
    float2* gates   = (float2*)ws;                                // 640 B
    float*  partial = (float*)(ws + 1024);                        // 512*20*4 = 40 KB
    float2* buf0    = (float2*)(ws + 65536);                      // 8 MB
    float2* buf1    = (float2*)(ws + 65536 + (size_t)(8u << 20)); // 8 MB

    prep_gates<<<1, 32, 0, stream>>>(x, gates);
    // layer 1 folded into product state; layer 2:
    stageA<0><<<512, 256, 0, stream>>>(buf1 /*unused*/, buf0, gates);
    stageB<0><<<512, 256, 0, stream>>>(buf0, gates, nullptr);
    // layer 3 (perm folded into A read):
    stageA<1><<<512, 256, 0, stream>>>(buf0, buf1, gates);
    stageB<0><<<512, 256, 0, stream>>>(buf1, gates, nullptr);
    // layer 4 (+ fused expectation, final perm folded):
    stageA<1><<<512, 256, 0, stream>>>(buf1, buf0, gates);
    stageB<1><<<512, 256, 0, stream>>>(buf0, gates, partial);
    reduce_out<<<1, 512, 0, stream>>>(partial, out);
}

// Round 6
// 87.388 us; speedup vs baseline: 1.0405x; 1.0405x over previous
//
#include <hip/hip_runtime.h>

// 20-qubit feature map, 4 layers (RX·RY per wire + CNOT chain), <Z_i> outputs.
// wire w <-> bit (19-w). CNOT chain == gray perm: new[y] = old[y ^ (y>>1)].
// R6: 4 fused gate passes. Key identity: a layer-(L+1) gate on bit b, seen one
// perm earlier, pairs z <-> z^(3<<(b-1)) (b=0: z^1), with the y_b=0 role given
// by parity XOR_{j>=b} z_j. Conjugated gates commute, so order inside the
// masked phase is free; plain gates of the earlier layer must all precede them.
// Schedule: P1(A:{0..11}): product state + L2 b0..11
//           P2(B:{0,1,2,11..19}, in-place): L2 b12..19 + masked L3 {0,1,2,12..19}
//           P3(A): gray-fold read + L3 b3..11 + masked L4 b0..11
//           P4(B): masked L4 b12..19 + expectation (invgray^2 signs)

#define NW 20

__device__ __forceinline__ float2 cmul(float2 a, float2 b) {
    return make_float2(a.x*b.x - a.y*b.y, a.x*b.y + a.y*b.x);
}

__device__ __forceinline__ float2 rowmul(float2 u, float2 a, float2 v, float2 b) {
    return make_float2(u.x*a.x - u.y*a.y + v.x*b.x - v.y*b.y,
                       u.x*a.y + u.y*a.x + v.x*b.y + v.y*b.x);
}

__device__ __forceinline__ void apply_gate(float2& a0, float2& a1,
                                           float2 u00, float2 u01,
                                           float2 u10, float2 u11) {
    float2 b0 = rowmul(u00, a0, u01, a1);
    float2 b1 = rowmul(u10, a0, u11, a1);
    a0 = b0; a1 = b1;
}

__device__ __forceinline__ float2 shflx(float2 v, int m) {
    float2 r;
    r.x = __shfl_xor(v.x, m, 64);
    r.y = __shfl_xor(v.y, m, 64);
    return r;
}

// suffix-XOR: bit b of result = XOR_{j>=b} x_j
__device__ __forceinline__ unsigned sfx(unsigned x) {
    x ^= x >> 1; x ^= x >> 2; x ^= x >> 4; x ^= x >> 8; x ^= x >> 16; return x;
}
// step-2 suffix-XOR: bit b = XOR_{j>=b, j==b mod 2} x_j  (= invgray^2 bit map)
__device__ __forceinline__ unsigned pfx2(unsigned x) {
    x ^= x >> 2; x ^= x >> 4; x ^= x >> 8; x ^= x >> 16; return x;
}

// plain gate pairing reg-bit A (R4-verified)
template<int A>
__device__ __forceinline__ void gate_regbit(float2 (&amp)[8], const float2* __restrict__ Gw) {
    float2 u00 = Gw[0], u01 = Gw[1], u10 = Gw[2], u11 = Gw[3];
    #pragma unroll
    for (int r = 0; r < 8; r++)
        if (!(r & (1 << A)))
            apply_gate(amp[r], amp[r | (1 << A)], u00, u01, u10, u11);
}

// butterfly: swap reg-bit A with lane bit LM (R4-verified)
template<int A, int LM>
__device__ __forceinline__ void swap_reg_lane(float2 (&amp)[8], unsigned lane) {
    bool hb = (lane & (unsigned)LM) != 0u;
    #pragma unroll
    for (int r = 0; r < 8; r++) {
        if (!(r & (1 << A))) {
            float2 lo = amp[r], hi = amp[r | (1 << A)];
            float2 xs = hb ? lo : hi;
            float2 ys = shflx(xs, LM);
            amp[r]            = hb ? ys : lo;
            amp[r | (1 << A)] = hb ? hi : ys;
        }
    }
}

// masked gate, pair mask M entirely in regs. SEL = reg-bit holding z_b,
// RH = reg-bits of z_j (j>b). Rk = XOR_{j>b} of the non-reg z bits.
template<int M, int SEL, int RH>
__device__ __forceinline__ void gate_mreg(float2 (&amp)[8], const float2* __restrict__ Gw,
                                          unsigned Rk) {
    float2 u00 = Gw[0], u01 = Gw[1], u10 = Gw[2], u11 = Gw[3];
    #pragma unroll
    for (int r = 0; r < 8; r++) {
        if (r & SEL) continue;
        int rp = r ^ M;
        unsigned fl = (Rk + (unsigned)__popc((unsigned)r & (unsigned)RH)) & 1u;
        if (fl == 0u) apply_gate(amp[r], amp[rp], u00, u01, u10, u11);
        else          apply_gate(amp[rp], amp[r], u00, u01, u10, u11);
    }
}

// masked gate, pair mask entirely in lane bits (LM). myzb = this thread's z_b,
// RH = reg-bits of z_j (j>b), Rk = XOR_{j>b} of non-reg z bits.
template<int LM, int RH>
__device__ __forceinline__ void gate_mlane(float2 (&amp)[8], const float2* __restrict__ Gw,
                                           unsigned myzb, unsigned Rk) {
    float2 u00 = Gw[0], u01 = Gw[1], u10 = Gw[2], u11 = Gw[3];
    #pragma unroll
    for (int r = 0; r < 8; r++) {
        float2 part = shflx(amp[r], LM);
        unsigned fl = (Rk + (unsigned)__popc((unsigned)r & (unsigned)RH)) & 1u;
        float2 mine = amp[r];
        amp[r] = ((myzb ^ fl) == 0u) ? rowmul(u00, mine, u01, part)
                                     : rowmul(u10, part, u11, mine);
    }
}

// U = RY(x)*RX(x), half-angle h = x/2. G[w*4 + r*2 + c] = U^w[r][c].
__global__ void prep_gates(const float* __restrict__ x, float2* __restrict__ G) {
    int w = threadIdx.x;
    if (w < NW) {
        float h = 0.5f * x[w];
        float c = cosf(h), s = sinf(h);
        float cc = c*c, ss = s*s, cs = c*s;
        G[w*4+0] = make_float2(cc,  ss);
        G[w*4+1] = make_float2(-cs, -cs);
        G[w*4+2] = make_float2(cs,  -cs);
        G[w*4+3] = make_float2(cc,  -ss);
    }
}

// P1: A-geometry (owns {0..11}, fixed z12..19 = H). Product state (L1 folded)
// + L2 gates b0..11. R4-verified stageA<0> verbatim.
__global__ __launch_bounds__(512) void passA1(float2* __restrict__ dst,
                                              const float2* __restrict__ G) {
    __shared__ float2 lds[4096];
    const unsigned t = threadIdx.x;
    const unsigned lane = t & 63u, wv = t >> 6;
    const unsigned H   = blockIdx.x;
    const unsigned Hp  = H ^ (H >> 1);
    const unsigned inj = (H & 1u) << 11;
    const unsigned lb  = (wv << 9) | (lane << 3);
    const unsigned gb  = (lb ^ (lb >> 1)) ^ inj;

    float2 amp[8];
    {
        float2 P = make_float2(1.0f, 0.0f);
        #pragma unroll
        for (int b = 12; b <= 19; b++)
            P = cmul(P, G[(19-b)*4 + (int)((Hp >> (b-12)) & 1u)*2]);
        #pragma unroll
        for (int b = 3; b <= 11; b++)
            P = cmul(P, G[(19-b)*4 + (int)((gb >> b) & 1u)*2]);
        float2 Tt[8];
        #pragma unroll
        for (int j = 0; j < 8; j++) {
            float2 v = cmul(G[18*4 + ((j>>1)&1)*2], G[19*4 + (j&1)*2]);
            v = cmul(G[17*4 + ((j>>2)&1)*2], v);
            Tt[j] = cmul(P, v);
        }
        bool f = (gb & 4u) != 0u;
        amp[0] = f ? Tt[4] : Tt[0];  amp[1] = f ? Tt[5] : Tt[1];
        amp[2] = f ? Tt[7] : Tt[3];  amp[3] = f ? Tt[6] : Tt[2];
        amp[4] = f ? Tt[2] : Tt[6];  amp[5] = f ? Tt[3] : Tt[7];
        amp[6] = f ? Tt[1] : Tt[5];  amp[7] = f ? Tt[0] : Tt[4];
    }
    gate_regbit<0>(amp, G + 19*4);
    gate_regbit<1>(amp, G + 18*4);
    gate_regbit<2>(amp, G + 17*4);
    swap_reg_lane<0,1>(amp, lane);
    swap_reg_lane<1,2>(amp, lane);
    swap_reg_lane<2,4>(amp, lane);
    gate_regbit<0>(amp, G + 16*4);
    gate_regbit<1>(amp, G + 15*4);
    gate_regbit<2>(amp, G + 14*4);
    swap_reg_lane<0,8>(amp, lane);
    swap_reg_lane<1,16>(amp, lane);
    swap_reg_lane<2,32>(amp, lane);
    gate_regbit<0>(amp, G + 13*4);
    gate_regbit<1>(amp, G + 12*4);
    gate_regbit<2>(amp, G + 11*4);
    #pragma unroll
    for (int k = 0; k < 8; k++) lds[(wv << 9) | ((unsigned)k << 6) | lane] = amp[k];
    __syncthreads();
    #pragma unroll
    for (int k = 0; k < 8; k++) amp[k] = lds[((unsigned)k << 9) | (wv << 6) | lane];
    gate_regbit<0>(amp, G + 10*4);
    gate_regbit<1>(amp, G +  9*4);
    gate_regbit<2>(amp, G +  8*4);
    float2* d = dst + ((size_t)H << 12);
    #pragma unroll
    for (int k = 0; k < 8; k++) d[((unsigned)k << 9) | (wv << 6) | lane] = amp[k];
}

// P2: B-geometry (owns {0,1,2,11..19}, fixed z3..10 = bb), in-place, frame f1.
// Plain L2 b12..19, then masked L3 b in {0,1,2,12..19}.
__global__ __launch_bounds__(512) void passB2(float2* __restrict__ st,
                                              const float2* __restrict__ G) {
    __shared__ float2 lds[4096];
    const unsigned t = threadIdx.x, lane = t & 63u, wv = t >> 6;
    const unsigned bb = blockIdx.x;
    const unsigned l012 = lane & 7u;
    const unsigned l3 = (lane >> 3) & 1u, l4 = (lane >> 4) & 1u, l5 = (lane >> 5) & 1u;
    const unsigned w0 = wv & 1u, w1 = (wv >> 1) & 1u, w2 = (wv >> 2) & 1u;

    // load map: l012=z012, bb=z3..10, w0=z11, k=z{12,13,14}, l3=z15, l4=z16, l5=z17, w1=z18, w2=z19
    float2 amp[8];
    const unsigned base = l012 | (bb << 3) | (w0 << 11) | (l3 << 15) | (l4 << 16)
                        | (l5 << 17) | (w1 << 18) | (w2 << 19);
    #pragma unroll
    for (int k = 0; k < 8; k++)
        amp[k] = st[base | ((unsigned)(k & 1) << 12) | ((unsigned)((k >> 1) & 1) << 13)
                         | ((unsigned)(k >> 2) << 14)];

    gate_regbit<0>(amp, G + 7*4);    // plain z12
    gate_regbit<1>(amp, G + 6*4);    // z13
    gate_regbit<2>(amp, G + 5*4);    // z14
    swap_reg_lane<0, 8>(amp, lane);  // 12<->15
    swap_reg_lane<1,16>(amp, lane);  // 13<->16
    swap_reg_lane<2,32>(amp, lane);  // 14<->17  -> regs={15,16,17}, l3=12,l4=13,l5=14
    gate_regbit<0>(amp, G + 4*4);    // z15
    gate_regbit<1>(amp, G + 3*4);    // z16
    gate_regbit<2>(amp, G + 2*4);    // z17
    // LDS-X1: write a0..5=lane(z012,12,13,14), a6..8=k(z15,16,17), a9..11=wv(z11,18,19)
    #pragma unroll
    for (int k = 0; k < 8; k++) lds[lane | ((unsigned)k << 6) | (wv << 9)] = amp[k];
    __syncthreads();
    // read: regs'={18,19,11}, wv'={15,16,17}
    #pragma unroll
    for (int k = 0; k < 8; k++)
        amp[k] = lds[lane | (w0 << 6) | (w1 << 7) | (w2 << 8)
                     | ((unsigned)((k >> 2) & 1) << 9) | ((unsigned)(k & 1) << 10)
                     | ((unsigned)((k >> 1) & 1) << 11)];
    __syncthreads();
    // map: l3=z12, l4=z13, l5=z14, wv={15,16,17}, k0=z18, k1=z19, k2=z11
    gate_regbit<0>(amp, G + 1*4);    // plain z18
    gate_regbit<1>(amp, G + 0*4);    // plain z19 -> all L2 done
    {
        unsigned zk = l012 | (bb << 3) | (l3 << 12) | (l4 << 13) | (l5 << 14)
                    | (w0 << 15) | (w1 << 16) | (w2 << 17);
        unsigned T = sfx(zk);
        gate_mlane<1, 7>(amp, G + 19*4, lane & 1u,        (T >> 1) & 1u);  // b0
        gate_mlane<3, 7>(amp, G + 18*4, (lane >> 1) & 1u, (T >> 2) & 1u);  // b1
        gate_mlane<6, 7>(amp, G + 17*4, (lane >> 2) & 1u, (T >> 3) & 1u);  // b2
        gate_mlane<24, 3>(amp, G + 6*4, l4, (T >> 14) & 1u);               // b13 {12,13}
        gate_mlane<48, 3>(amp, G + 5*4, l5, (T >> 15) & 1u);               // b14 {13,14}
        gate_mreg<3, 2, 0>(amp, G + 0*4, 0u);                              // b19 {18,19}
    }
    // LDS-X2: write a3=z12,a4=z13,a5=z14, a6..8=k(z18,19,11), a9..11=wv(z15,16,17)
    #pragma unroll
    for (int k = 0; k < 8; k++) lds[lane | ((unsigned)k << 6) | (wv << 9)] = amp[k];
    __syncthreads();
    // read: regs'={14,15,16}, l3'=17, l4'=18, l5'=11, wv'={12,13,19}
    #pragma unroll
    for (int k = 0; k < 8; k++)
        amp[k] = lds[l012 | (w0 << 3) | (w1 << 4) | ((unsigned)(k & 1) << 5)
                     | (l4 << 6) | (w2 << 7) | (l5 << 8)
                     | ((unsigned)((k >> 1) & 1) << 9) | ((unsigned)(k >> 2) << 10)
                     | (l3 << 11)];
    __syncthreads();
    {
        unsigned zk2 = l012 | (bb << 3) | (l3 << 17) | (l4 << 18) | (l5 << 11)
                     | (w0 << 12) | (w1 << 13) | (w2 << 19);
        unsigned T2 = sfx(zk2);
        gate_mreg<3, 2, 4>(amp, G + 4*4, (T2 >> 16) & 1u);   // b15 {14,15}
        gate_mreg<6, 4, 0>(amp, G + 3*4, (T2 >> 17) & 1u);   // b16 {15,16}
        gate_mlane<24, 0>(amp, G + 1*4, l4, (T2 >> 19) & 1u);// b18 {17,18} (l3,l4)
    }
    // LDS-X3: write a3=z17,a4=z18,a5=z11, a6..8=k(z14,15,16), a9..11=wv(z12,13,19)
    #pragma unroll
    for (int k = 0; k < 8; k++) lds[lane | ((unsigned)k << 6) | (wv << 9)] = amp[k];
    __syncthreads();
    // read: regs'={11,12,13}, l3'=16, l4'=17, l5'=14, wv'={15,18,19}
    #pragma unroll
    for (int k = 0; k < 8; k++)
        amp[k] = lds[l012 | (l4 << 3) | (w1 << 4) | ((unsigned)(k & 1) << 5)
                     | (l5 << 6) | (w0 << 7) | (l3 << 8)
                     | ((unsigned)((k >> 1) & 1) << 9) | ((unsigned)(k >> 2) << 10)
                     | (w2 << 11)];
    {
        unsigned zk3 = l012 | (bb << 3) | (l3 << 16) | (l4 << 17) | (l5 << 14)
                     | (w0 << 15) | (w1 << 18) | (w2 << 19);
        unsigned T3 = sfx(zk3);
        gate_mreg<3, 2, 4>(amp, G + 7*4, (T3 >> 13) & 1u);    // b12 {11,12}
        gate_mlane<24, 0>(amp, G + 2*4, l4, (T3 >> 18) & 1u); // b17 {16,17} (l3,l4)
    }
    // store f1-logical: k0=z11,k1=z12,k2=z13, l5=z14, w0=z15, l3=z16, l4=z17, w1=z18, w2=z19
    const unsigned sb = l012 | (bb << 3) | (l5 << 14) | (w0 << 15) | (l3 << 16)
                      | (l4 << 17) | (w1 << 18) | (w2 << 19);
    #pragma unroll
    for (int k = 0; k < 8; k++)
        st[sb | ((unsigned)(k & 1) << 11) | ((unsigned)((k >> 1) & 1) << 12)
              | ((unsigned)(k >> 2) << 13)] = amp[k];
}

// P3: A-geometry, gray-fold read (f1->f2), plain L3 b3..11, masked L4 b0..11.
__global__ __launch_bounds__(512) void passA3(const float2* __restrict__ src,
                                              float2* __restrict__ dst,
                                              const float2* __restrict__ G) {
    __shared__ float2 lds[4096];
    const unsigned t = threadIdx.x, lane = t & 63u, wv = t >> 6;
    const unsigned H   = blockIdx.x;
    const unsigned Hp  = H ^ (H >> 1);
    const unsigned inj = (H & 1u) << 11;
    const unsigned lb  = (wv << 9) | (lane << 3);
    const unsigned gb  = (lb ^ (lb >> 1)) ^ inj;

    float2 amp[8];   // R4-verified MODE1 gray gather
    {
        const float4* q = (const float4*)(src + ((size_t)Hp << 12) + (gb & ~7u));
        float4 q0 = q[0], q1 = q[1], q2 = q[2], q3 = q[3];
        float2 e0 = make_float2(q0.x,q0.y), e1 = make_float2(q0.z,q0.w);
        float2 e2 = make_float2(q1.x,q1.y), e3 = make_float2(q1.z,q1.w);
        float2 e4 = make_float2(q2.x,q2.y), e5 = make_float2(q2.z,q2.w);
        float2 e6 = make_float2(q3.x,q3.y), e7 = make_float2(q3.z,q3.w);
        bool f = (gb & 4u) != 0u;
        amp[0] = f ? e4 : e0;  amp[1] = f ? e5 : e1;
        amp[2] = f ? e7 : e3;  amp[3] = f ? e6 : e2;
        amp[4] = f ? e2 : e6;  amp[5] = f ? e3 : e7;
        amp[6] = f ? e1 : e5;  amp[7] = f ? e0 : e4;
    }
    // map: regs=z{0,1,2}, lanes=z{3..8}, wv=z{9,10,11}; no gates on z0..2 here.
    swap_reg_lane<0,1>(amp, lane);
    swap_reg_lane<1,2>(amp, lane);
    swap_reg_lane<2,4>(amp, lane);   // regs={3,4,5}, l012={0,1,2}
    gate_regbit<0>(amp, G + 16*4);   // b3
    gate_regbit<1>(amp, G + 15*4);   // b4
    gate_regbit<2>(amp, G + 14*4);   // b5
    swap_reg_lane<0,8>(amp, lane);
    swap_reg_lane<1,16>(amp, lane);
    swap_reg_lane<2,32>(amp, lane);  // regs={6,7,8}, l345={3,4,5}
    gate_regbit<0>(amp, G + 13*4);   // b6
    gate_regbit<1>(amp, G + 12*4);   // b7
    gate_regbit<2>(amp, G + 11*4);   // b8
    #pragma unroll
    for (int k = 0; k < 8; k++) lds[lane | ((unsigned)k << 6) | (wv << 9)] = amp[k];
    __syncthreads();
    #pragma unroll
    for (int k = 0; k < 8; k++) amp[k] = lds[lane | (wv << 6) | ((unsigned)k << 9)];
    __syncthreads();
    // map: l=z0..5, wv={6,7,8}, regs={9,10,11}
    gate_regbit<0>(amp, G + 10*4);   // b9
    gate_regbit<1>(amp, G +  9*4);   // b10
    gate_regbit<2>(amp, G +  8*4);   // b11  -> all plain L3 done
    {
        unsigned zk = lane | (wv << 6) | (H << 12);
        unsigned T = sfx(zk);
        gate_mlane<1, 7>(amp, G + 19*4, lane & 1u,        (T >> 1) & 1u);  // b0
        gate_mlane<3, 7>(amp, G + 18*4, (lane >> 1) & 1u, (T >> 2) & 1u);  // b1
        gate_mlane<6, 7>(amp, G + 17*4, (lane >> 2) & 1u, (T >> 3) & 1u);  // b2
        gate_mlane<12, 7>(amp, G + 16*4, (lane >> 3) & 1u, (T >> 4) & 1u); // b3
        gate_mlane<24, 7>(amp, G + 15*4, (lane >> 4) & 1u, (T >> 5) & 1u); // b4
        gate_mlane<48, 7>(amp, G + 14*4, (lane >> 5) & 1u, (T >> 6) & 1u); // b5
        gate_mreg<3, 2, 4>(amp, G + 9*4, (T >> 11) & 1u);                  // b10 {9,10}
        gate_mreg<6, 4, 0>(amp, G + 8*4, (T >> 12) & 1u);                  // b11 {10,11}
    }
    // LDS-X2: write a_i = z_i
    #pragma unroll
    for (int k = 0; k < 8; k++) lds[lane | (wv << 6) | ((unsigned)k << 9)] = amp[k];
    __syncthreads();
    // read: regs'={5,6,7}, l3'=8, l4'=9, l5'=3, w0'=4, w1'=10, w2'=11
    const unsigned l3v = (lane >> 3) & 1u, l4v = (lane >> 4) & 1u, l5v = (lane >> 5) & 1u;
    const unsigned w0v = wv & 1u, w1v = (wv >> 1) & 1u, w2v = (wv >> 2) & 1u;
    #pragma unroll
    for (int k = 0; k < 8; k++)
        amp[k] = lds[(lane & 7u) | (l5v << 3) | (w0v << 4)
                     | ((unsigned)(k & 1) << 5) | ((unsigned)((k >> 1) & 1) << 6)
                     | ((unsigned)(k >> 2) << 7)
                     | (l3v << 8) | (l4v << 9) | (w1v << 10) | (w2v << 11)];
    {
        unsigned zkB = (lane & 7u) | (l5v << 3) | (w0v << 4) | (l3v << 8) | (l4v << 9)
                     | (w1v << 10) | (w2v << 11) | (H << 12);
        unsigned TB = sfx(zkB);
        gate_mreg<3, 2, 4>(amp, G + 13*4, (TB >> 7) & 1u);   // b6 {5,6}
        gate_mreg<6, 4, 0>(amp, G + 12*4, (TB >> 8) & 1u);   // b7 {6,7}
    }
    swap_reg_lane<0, 8>(amp, lane);   // k0: z5 <-> l3: z8  -> k0=z8, l3=z5
    {
        unsigned zkC = (lane & 7u) | (l5v << 3) | (w0v << 4) | (l3v << 5) | (l4v << 9)
                     | (w1v << 10) | (w2v << 11) | (H << 12);
        unsigned TC = sfx(zkC);
        gate_mreg<5, 1, 0>(amp, G + 11*4, (TC >> 9) & 1u);   // b8 {7,8}
    }
    swap_reg_lane<1, 16>(amp, lane);  // k1: z6 <-> l4: z9 -> k1=z9, l4=z6
    {
        unsigned zkD = (lane & 7u) | (l5v << 3) | (w0v << 4) | (l3v << 5) | (l4v << 6)
                     | (w1v << 10) | (w2v << 11) | (H << 12);
        unsigned TD = sfx(zkD);
        gate_mreg<3, 2, 0>(amp, G + 10*4, (TD >> 10) & 1u);  // b9 {8,9}
    }
    // store f2-logical: l012=z012, l5=z3, w0=z4, l3=z5, l4=z6, k2=z7, k0=z8, k1=z9, w1=z10, w2=z11
    const unsigned sb = (lane & 7u) | (l5v << 3) | (w0v << 4) | (l3v << 5) | (l4v << 6)
                      | (w1v << 10) | (w2v << 11) | (H << 12);
    #pragma unroll
    for (int k = 0; k < 8; k++)
        dst[sb | ((unsigned)((k >> 2) & 1) << 7) | ((unsigned)(k & 1) << 8)
              | ((unsigned)((k >> 1) & 1) << 9)] = amp[k];
}

// P4: B-geometry, frame f2, masked L4 b12..19, expectation with invgray^2 signs.
__global__ __launch_bounds__(512) void passB4(const float2* __restrict__ st,
                                              const float2* __restrict__ G,
                                              float* __restrict__ partial) {
    __shared__ float2 lds[4096];
    const unsigned t = threadIdx.x, lane = t & 63u, wv = t >> 6;
    const unsigned bb = blockIdx.x;
    const unsigned l012 = lane & 7u;
    const unsigned l3 = (lane >> 3) & 1u, l4 = (lane >> 4) & 1u, l5 = (lane >> 5) & 1u;
    const unsigned w0 = wv & 1u, w1 = (wv >> 1) & 1u, w2 = (wv >> 2) & 1u;

    float2 amp[8];
    const unsigned base = l012 | (bb << 3) | (w0 << 11) | (l3 << 15) | (l4 << 16)
                        | (l5 << 17) | (w1 << 18) | (w2 << 19);
    #pragma unroll
    for (int k = 0; k < 8; k++)
        amp[k] = st[base | ((unsigned)(k & 1) << 12) | ((unsigned)((k >> 1) & 1) << 13)
                         | ((unsigned)(k >> 2) << 14)];
    // map: k={12,13,14}, l3=15, l4=16, l5=17, w0=11, w1=18, w2=19
    {
        unsigned T = sfx(base);
        gate_mreg<3, 2, 4>(amp, G + 6*4, (T >> 14) & 1u);    // b13 {12,13}
        gate_mreg<6, 4, 0>(amp, G + 5*4, (T >> 15) & 1u);    // b14 {13,14}
    }
    swap_reg_lane<0, 8>(amp, lane);   // z12 <-> z15: regs={15,13,14}, l3=12
    {
        unsigned zkB = l012 | (bb << 3) | (w0 << 11) | (l3 << 12) | (l4 << 16)
                     | (l5 << 17) | (w1 << 18) | (w2 << 19);
        unsigned TB = sfx(zkB);
        gate_mreg<5, 1, 0>(amp, G + 4*4, (TB >> 16) & 1u);   // b15 {14,15}
    }
    swap_reg_lane<1, 16>(amp, lane);  // z13 <-> z16: regs={15,16,14}, l4=13
    {
        unsigned zkC = l012 | (bb << 3) | (w0 << 11) | (l3 << 12) | (l4 << 13)
                     | (l5 << 17) | (w1 << 18) | (w2 << 19);
        unsigned TC = sfx(zkC);
        gate_mreg<3, 2, 0>(amp, G + 3*4, (TC >> 17) & 1u);   // b16 {15,16}
    }
    swap_reg_lane<2, 32>(amp, lane);  // z14 <-> z17: regs={15,16,17}, l5=14
    {
        unsigned zkD = l012 | (bb << 3) | (w0 << 11) | (l3 << 12) | (l4 << 13)
                     | (l5 << 14) | (w1 << 18) | (w2 << 19);
        unsigned TD = sfx(zkD);
        gate_mreg<6, 4, 0>(amp, G + 2*4, (TD >> 18) & 1u);   // b17 {16,17}
    }
    // LDS-X1: write a3=z12, a4=z13, a5=z14, a6..8=k(z15,16,17), a9..11=wv(z11,18,19)
    #pragma unroll
    for (int k = 0; k < 8; k++) lds[lane | ((unsigned)k << 6) | (wv << 9)] = amp[k];
    __syncthreads();
    // read: regs'={17,18,19}, l3'=11, l4'=12, l5'=13, wv'={14,15,16}
    #pragma unroll
    for (int k = 0; k < 8; k++)
        amp[k] = lds[l012 | (l4 << 3) | (l5 << 4) | (w0 << 5) | (w1 << 6) | (w2 << 7)
                     | ((unsigned)(k & 1) << 8) | (l3 << 9)
                     | ((unsigned)((k >> 1) & 1) << 10) | ((unsigned)(k >> 2) << 11)];
    const unsigned zkE = l012 | (bb << 3) | (l3 << 11) | (l4 << 12) | (l5 << 13)
                       | (w0 << 14) | (w1 << 15) | (w2 << 16);
    {
        unsigned TE = sfx(zkE);
        gate_mreg<3, 2, 4>(amp, G + 1*4, 0u);                 // b18 {17,18}
        gate_mreg<6, 4, 0>(amp, G + 0*4, 0u);                 // b19 {18,19}
        gate_mlane<24, 7>(amp, G + 7*4, l4, (TE >> 13) & 1u); // b12 {11,12} (l3,l4)
    }
    // expectation: y = invgray^2(z); regs k0=z17, k1=z18, k2=z19.
    float p[8];
    #pragma unroll
    for (int r = 0; r < 8; r++) p[r] = amp[r].x*amp[r].x + amp[r].y*amp[r].y;
    float E   = (p[0]+p[1]+p[4]+p[5]) - (p[2]+p[3]+p[6]+p[7]);   // (-1)^{z18}
    float Do  = (p[0]+p[2]+p[5]+p[7]) - (p[1]+p[3]+p[4]+p[6]);   // (-1)^{z17^z19}
    float S19 = (p[0]+p[1]+p[2]+p[3]) - (p[4]+p[5]+p[6]+p[7]);   // (-1)^{z19}
    unsigned t2 = pfx2(zkE);
    float acc[NW];
    acc[0] = S19;
    #pragma unroll
    for (int w = 1; w < NW; w++) {
        int b = 19 - w;
        float v = (b & 1) ? Do : E;
        acc[w] = ((t2 >> b) & 1u) ? -v : v;
    }
    __syncthreads();                  // LDS reuse for reduction
    float* red = (float*)lds;
    #pragma unroll
    for (int w = 0; w < NW; w++) {
        float s = acc[w];
        #pragma unroll
        for (int off = 32; off; off >>= 1) s += __shfl_down(s, off, 64);
        if (lane == 0) red[wv*NW + w] = s;
    }
    __syncthreads();
    if (t < NW) {
        float s = 0.0f;
        #pragma unroll
        for (int v8 = 0; v8 < 8; v8++) s += red[v8*NW + (int)t];
        partial[bb*NW + t] = s;
    }
}

__global__ __launch_bounds__(256) void reduce_out(const float* __restrict__ partial,
                                                  float* __restrict__ out) {
    __shared__ float red[4*NW];
    unsigned t = threadIdx.x;
    float vals[NW];
    #pragma unroll
    for (int w = 0; w < NW; w++) vals[w] = partial[t*NW + w];
    #pragma unroll
    for (int w = 0; w < NW; w++) {
        float v = vals[w];
        #pragma unroll
        for (int off = 32; off; off >>= 1) v += __shfl_down(v, off, 64);
        if ((t & 63u) == 0u) red[(t >> 6)*NW + w] = v;
    }
    __syncthreads();
    if (t < NW) out[t] = red[t] + red[NW+t] + red[2*NW+t] + red[3*NW+t];
}

extern "C" void kernel_launch(void* const* d_in, const int* in_sizes, int n_in,
                              void* d_out, int out_size, void* d_ws, size_t ws_size,
                              hipStream_t stream) {
    (void)in_sizes; (void)n_in; (void)out_size; (void)ws_size;
    const float* x = (const float*)d_in[0];
    float* out = (float*)d_out;

    char* ws = (char*)d_ws;
    float2* gates   = (float2*)ws;                                // 640 B
    float*  partial = (float*)(ws + 1024);                        // 20 KB
    float2* buf0    = (float2*)(ws + 65536);                      // 8 MB (f1)
    float2* buf1    = (float2*)(ws + 65536 + (size_t)(8u << 20)); // 8 MB (f2)

    prep_gates<<<1, 32, 0, stream>>>(x, gates);
    passA1<<<256, 512, 0, stream>>>(buf0, gates);           // L1 folded + L2 b0..11
    passB2<<<256, 512, 0, stream>>>(buf0, gates);           // L2 b12..19 + L3 masked (in-place)
    passA3<<<256, 512, 0, stream>>>(buf0, buf1, gates);     // fold + L3 b3..11 + L4 masked b0..11
    passB4<<<256, 512, 0, stream>>>(buf1, gates, partial);  // L4 masked b12..19 + expectation
    reduce_out<<<1, 256, 0, stream>>>(partial, out);
}